// Round 13
// baseline (97.673 us; speedup 1.0000x reference)
//
#include <hip/hip_runtime.h>
#include <math.h>

// Quantized softmax over axis 1 of x(8, 4096, 1024) fp32.
// Groups: (b, c) column, 8192 groups of 4096 elements (stride 1024 floats).
//
// Round-13 = Round-12 (95.2us) with two micro-levers:
//   - P2 at JC2=32 / 1024 blocks (4 blocks/CU): the exp chain is ~12 dependent
//     VALU ops; 2 waves/SIMD (R12) under-hides its latency. psum 2MB->4MB.
//   - P3 loads all 16 rows of codes in one 16-deep batch (c4 = 1 VGPR each).
// Structure ledger: coop fusion dead (R10: grid sync ~50us each); col-slab
// dead (R9: +11us); row-chunk 5-kernel pipeline is the winning shape.
//   K1 p1: x (NT, 8-deep) -> codes(32MB) + [jc][g] max/min partials.
//   K2 r1: partials (c4-vectorized) -> gmv[g] + global amax_sub (atomicMax).
//   K3 p2: codes (16-deep) -> psum[128][8192] (32-row partial sums).
//   K4 r2: psum -> sarr[g] + global max/min s (atomics).
//   K5 p3: codes (16-deep) + scalars -> out (NT stores).
// Atomics: uint max/min only (order-independent -> deterministic).

typedef float       f4 __attribute__((ext_vector_type(4)));
typedef signed char c4 __attribute__((ext_vector_type(4)));

static constexpr int Bdim = 8;
static constexpr int Jdim = 4096;
static constexpr int Cdim = 1024;
static constexpr int NG   = Bdim * Cdim;       // 8192 groups

static constexpr int JC    = 16;               // rows per P1/P3 chunk
static constexpr int NJC   = Jdim / JC;        // 256
static constexpr int GRID1 = Bdim * NJC;       // 2048
static constexpr int JC2   = 32;               // rows per P2 chunk
static constexpr int NJC2  = Jdim / JC2;       // 128
static constexpr int GRID2 = Bdim * NJC2;      // 1024 (4 blocks/CU)

// ---- ws byte offsets (CODES_B kept at R12's location; psum slack is fine) ----
static constexpr size_t SC_B    = 0;                               // f32[3]
static constexpr size_t GMV_B   = 4096;                            // f32[8192] gmax CODE
static constexpr size_t SARR_B  = GMV_B + (size_t)NG * 4;          // f32[8192]
static constexpr size_t PMAX_B  = 131072;                          // i8[256][8192]
static constexpr size_t PMIN_B  = PMAX_B + (size_t)NJC * NG;
static constexpr size_t PSUM_B  = PMIN_B + (size_t)NJC * NG;       // f32[128][8192] = 4MB
static constexpr size_t CODES_B = PSUM_B + (size_t)NJC * NG * 4;   // i8 32MB
static constexpr size_t WS_NEED = CODES_B + (size_t)Bdim * Jdim * Cdim;  // ~44MB

__device__ __forceinline__ float code8f(float x, float sinv) {
    // int8 code as float; rintf = round-half-even matches jnp.round
    return fminf(fmaxf(rintf(x * sinv), -128.0f), 127.0f);
}
// e_q = fq16(exp(fq16(clip(xq - gmax, -12, 0)))); scale_e = 1/32767 exactly
// (group-max element has sub==0 -> e==1 -> absmax(e)==1).
__device__ __forceinline__ float eq_from(float xq, float gmv, float ssub_inv, float ssub) {
    float sub = fminf(fmaxf(xq - gmv, -12.0f), 0.0f);
    float q   = rintf(sub * ssub_inv);
    float e   = __expf(q * ssub);
    return rintf(e * 32767.0f) * (1.0f / 32767.0f);
}
__device__ __forceinline__ f4 fmax4v(f4 a, f4 b) {
    f4 r; r[0]=fmaxf(a[0],b[0]); r[1]=fmaxf(a[1],b[1]);
    r[2]=fmaxf(a[2],b[2]); r[3]=fmaxf(a[3],b[3]); return r;
}
__device__ __forceinline__ f4 fmin4v(f4 a, f4 b) {
    f4 r; r[0]=fminf(a[0],b[0]); r[1]=fminf(a[1],b[1]);
    r[2]=fminf(a[2],b[2]); r[3]=fminf(a[3],b[3]); return r;
}

// ---------------- K1: quantize pass (unchanged from R12) ----------------
template <bool WC>
__global__ __launch_bounds__(256) void k_p1(const float* __restrict__ x,
                                            const float* __restrict__ scale,
                                            char* __restrict__ ws) {
    float* sc = (float*)(ws + SC_B);
    if (blockIdx.x == 0 && threadIdx.x == 0) {
        sc[0] = 0.0f;                        // amax_sub (atomicMax, >=0)
        sc[1] = 0.0f;                        // max_s    (atomicMax, >0)
        sc[2] = __int_as_float(0x7f800000);  // min_s = +inf (atomicMin)
    }
    const int b  = blockIdx.x / NJC;
    const int jc = blockIdx.x % NJC;
    const int c0 = threadIdx.x * 4;
    const float sinv = 1.0f / scale[0];
    const size_t base = ((size_t)(b * Jdim + jc * JC)) * Cdim + c0;
    signed char* codes = (signed char*)(ws + CODES_B);

    f4 vmax = {-1e30f, -1e30f, -1e30f, -1e30f};
    f4 vmin = { 1e30f,  1e30f,  1e30f,  1e30f};
#pragma unroll
    for (int r0 = 0; r0 < JC; r0 += 8) {
        f4 v[8];
#pragma unroll
        for (int j = 0; j < 8; ++j)                 // 8 loads in flight
            v[j] = __builtin_nontemporal_load(
                reinterpret_cast<const f4*>(x + base + (size_t)(r0 + j) * Cdim));
#pragma unroll
        for (int j = 0; j < 8; ++j) {
            f4 q;
            q[0] = code8f(v[j][0], sinv); q[1] = code8f(v[j][1], sinv);
            q[2] = code8f(v[j][2], sinv); q[3] = code8f(v[j][3], sinv);
            vmax = fmax4v(vmax, q); vmin = fmin4v(vmin, q);
            if (WC)
                *reinterpret_cast<c4*>(codes + base + (size_t)(r0 + j) * Cdim) =
                    (c4){(signed char)(int)q[0], (signed char)(int)q[1],
                         (signed char)(int)q[2], (signed char)(int)q[3]};
        }
    }
    const size_t pidx = (size_t)jc * NG + b * Cdim + c0;   // [jc][g] coalesced
    *reinterpret_cast<c4*>(ws + PMAX_B + pidx) =
        (c4){(signed char)(int)vmax[0], (signed char)(int)vmax[1],
             (signed char)(int)vmax[2], (signed char)(int)vmax[3]};
    *reinterpret_cast<c4*>(ws + PMIN_B + pidx) =
        (c4){(signed char)(int)vmin[0], (signed char)(int)vmin[1],
             (signed char)(int)vmin[2], (signed char)(int)vmin[3]};
}

// ---------------- K2: group gmax + global amax_sub (unchanged from R12) ----------------
__global__ __launch_bounds__(256) void k_r1(const float* __restrict__ scale,
                                            char* __restrict__ ws) {
    const signed char* pmax8 = (const signed char*)(ws + PMAX_B);
    const signed char* pmin8 = (const signed char*)(ws + PMIN_B);
    float* gmv = (float*)(ws + GMV_B);
    float* sc  = (float*)(ws + SC_B);

    const int qi  = threadIdx.x & 31;             // quad index
    const int sub = threadIdx.x >> 5;             // 0..7
    const size_t g4 = (size_t)blockIdx.x * 128 + qi * 4;

    int mx0 = -128, mx1 = -128, mx2 = -128, mx3 = -128;
    int mn0 =  127, mn1 =  127, mn2 =  127, mn3 =  127;
    for (int jc = sub; jc < NJC; jc += 8) {
        const c4 a = *reinterpret_cast<const c4*>(pmax8 + (size_t)jc * NG + g4);
        const c4 b = *reinterpret_cast<const c4*>(pmin8 + (size_t)jc * NG + g4);
        mx0 = max(mx0, (int)a[0]); mx1 = max(mx1, (int)a[1]);
        mx2 = max(mx2, (int)a[2]); mx3 = max(mx3, (int)a[3]);
        mn0 = min(mn0, (int)b[0]); mn1 = min(mn1, (int)b[1]);
        mn2 = min(mn2, (int)b[2]); mn3 = min(mn3, (int)b[3]);
    }
    __shared__ int smx[8][32][4], smn[8][32][4];
    smx[sub][qi][0] = mx0; smx[sub][qi][1] = mx1;
    smx[sub][qi][2] = mx2; smx[sub][qi][3] = mx3;
    smn[sub][qi][0] = mn0; smn[sub][qi][1] = mn1;
    smn[sub][qi][2] = mn2; smn[sub][qi][3] = mn3;
    __syncthreads();
    for (int off = 4; off; off >>= 1) {
        if (sub < off) {
#pragma unroll
            for (int i = 0; i < 4; ++i) {
                smx[sub][qi][i] = max(smx[sub][qi][i], smx[sub + off][qi][i]);
                smn[sub][qi][i] = min(smn[sub][qi][i], smn[sub + off][qi][i]);
            }
        }
        __syncthreads();
    }
    __shared__ float sd[32];
    if (sub == 0) {
        const float s = scale[0];
        f4 gq;
        float d = -1e30f;
#pragma unroll
        for (int i = 0; i < 4; ++i) {
            const float gx = (float)smx[0][qi][i];
            gq[i] = gx;
            d = fmaxf(d, fminf(12.0f, gx * s - (float)smn[0][qi][i] * s));
        }
        *reinterpret_cast<f4*>(gmv + g4) = gq;    // CODE values; consumers *s
        sd[qi] = d;
    }
    __syncthreads();
    if (threadIdx.x == 0) {
        float m = sd[0];
#pragma unroll
        for (int i = 1; i < 32; ++i) m = fmaxf(m, sd[i]);
        atomicMax(reinterpret_cast<unsigned int*>(sc + 0), __float_as_uint(m));
    }
}

// ---------------- K3: partial e_q sums, JC2=32, 1024 blocks ----------------
template <bool UC>
__global__ __launch_bounds__(256) void k_p2(const float* __restrict__ x,
                                            const float* __restrict__ scale,
                                            char* __restrict__ ws) {
    const int b  = blockIdx.x / NJC2;
    const int jq = blockIdx.x % NJC2;
    const int c0 = threadIdx.x * 4;
    const float s = scale[0];
    const float sinv = 1.0f / s;
    const float* sc  = (const float*)(ws + SC_B);
    const float* gmv = (const float*)(ws + GMV_B);
    float* psum = (float*)(ws + PSUM_B);
    const signed char* codes = (const signed char*)(ws + CODES_B);

    const float amax = fmaxf(sc[0], 1e-9f);
    const float ssub = amax / 32767.0f;
    const float ssub_inv = 1.0f / ssub;
    const f4 gmc = *reinterpret_cast<const f4*>(gmv + b * Cdim + c0);
    const f4 gm  = {gmc[0] * s, gmc[1] * s, gmc[2] * s, gmc[3] * s};
    const size_t base = ((size_t)(b * Jdim + jq * JC2)) * Cdim + c0;

    f4 acc = {0.f, 0.f, 0.f, 0.f};
#pragma unroll
    for (int r0 = 0; r0 < JC2; r0 += 16) {
        c4 qv[16];
        f4 xv[8];
        if (UC) {
#pragma unroll
            for (int j = 0; j < 16; ++j)            // 16 loads in flight (1 VGPR each)
                qv[j] = *reinterpret_cast<const c4*>(codes + base + (size_t)(r0 + j) * Cdim);
#pragma unroll
            for (int j = 0; j < 16; ++j) {
                acc[0] += eq_from((float)qv[j][0] * s, gm[0], ssub_inv, ssub);
                acc[1] += eq_from((float)qv[j][1] * s, gm[1], ssub_inv, ssub);
                acc[2] += eq_from((float)qv[j][2] * s, gm[2], ssub_inv, ssub);
                acc[3] += eq_from((float)qv[j][3] * s, gm[3], ssub_inv, ssub);
            }
        } else {
#pragma unroll
            for (int h = 0; h < 16; h += 8) {
#pragma unroll
                for (int j = 0; j < 8; ++j)
                    xv[j] = *reinterpret_cast<const f4*>(x + base + (size_t)(r0 + h + j) * Cdim);
#pragma unroll
                for (int j = 0; j < 8; ++j) {
                    acc[0] += eq_from(code8f(xv[j][0], sinv) * s, gm[0], ssub_inv, ssub);
                    acc[1] += eq_from(code8f(xv[j][1], sinv) * s, gm[1], ssub_inv, ssub);
                    acc[2] += eq_from(code8f(xv[j][2], sinv) * s, gm[2], ssub_inv, ssub);
                    acc[3] += eq_from(code8f(xv[j][3], sinv) * s, gm[3], ssub_inv, ssub);
                }
            }
        }
    }
    *reinterpret_cast<f4*>(psum + (size_t)jq * NG + b * Cdim + c0) = acc;  // [jq][g]
}

// ---------------- K4: group sums + global max/min s (128 chunks) ----------------
__global__ __launch_bounds__(256) void k_r2(char* __restrict__ ws) {
    const float* psum = (const float*)(ws + PSUM_B);
    float* sarr = (float*)(ws + SARR_B);
    float* sc   = (float*)(ws + SC_B);

    const int ci  = threadIdx.x & 31;
    const int sub = threadIdx.x >> 5;
    const int g   = blockIdx.x * 32 + ci;

    float p = 0.0f;
    for (int ch = sub; ch < NJC2; ch += 8)         // ascending, step 8
        p += psum[(size_t)ch * NG + g];
    __shared__ float sp[8][32];
    sp[sub][ci] = p;
    __syncthreads();
    for (int off = 4; off; off >>= 1) {
        if (sub < off) sp[sub][ci] += sp[sub + off][ci];
        __syncthreads();
    }
    __shared__ float smx[32], smn[32];
    if (sub == 0) {
        const float tv = sp[0][ci];
        sarr[g] = tv;
        smx[ci] = tv; smn[ci] = tv;
    }
    __syncthreads();
    if (threadIdx.x == 0) {
        float mx = smx[0], mn = smn[0];
#pragma unroll
        for (int i = 1; i < 32; ++i) { mx = fmaxf(mx, smx[i]); mn = fminf(mn, smn[i]); }
        atomicMax(reinterpret_cast<unsigned int*>(sc + 1), __float_as_uint(mx));
        atomicMin(reinterpret_cast<unsigned int*>(sc + 2), __float_as_uint(mn));
    }
}

// ---------------- K5: output pass (16-deep code batch) ----------------
template <bool UC>
__global__ __launch_bounds__(256) void k_p3(const float* __restrict__ x,
                                            const float* __restrict__ scale,
                                            const char* __restrict__ ws,
                                            float* __restrict__ out) {
    const int b  = blockIdx.x / NJC;
    const int jc = blockIdx.x % NJC;
    const int c0 = threadIdx.x * 4;
    const float s = scale[0];
    const float sinv = 1.0f / s;
    const float* sc   = (const float*)(ws + SC_B);
    const float* gmv  = (const float*)(ws + GMV_B);
    const float* sarr = (const float*)(ws + SARR_B);
    const signed char* codes = (const signed char*)(ws + CODES_B);

    const float amax = fmaxf(sc[0], 1e-9f);
    const float ssub = amax / 32767.0f;
    const float ssub_inv = 1.0f / ssub;

    const float max_s = sc[1];
    const float min_s = sc[2];
    // fq monotone: min s_q = fq(min s); max r = 1/min s_q; max r_q = fq(max r)
    const float scale_s = fmaxf(max_s, 1e-9f) / 32767.0f;
    const float ss_inv  = 1.0f / scale_s;
    const float minsq   = fminf(fmaxf(rintf(min_s * ss_inv), -32768.0f), 32767.0f) * scale_s;
    const float maxr    = 1.0f / minsq;
    const float scale_r = fmaxf(maxr, 1e-9f) / 32767.0f;
    const float sr_inv  = 1.0f / scale_r;
    const float maxrq   = fminf(fmaxf(rintf(maxr * sr_inv), -32768.0f), 32767.0f) * scale_r;
    const float scale_out = fmaxf(maxrq, 1e-9f) / 127.0f;
    const float so_inv  = 1.0f / scale_out;

    const f4 gmc = *reinterpret_cast<const f4*>(gmv + b * Cdim + c0);
    const f4 gm  = {gmc[0] * s, gmc[1] * s, gmc[2] * s, gmc[3] * s};
    const f4 s4  = *reinterpret_cast<const f4*>(sarr + b * Cdim + c0);

    f4 rq;
#pragma unroll
    for (int i = 0; i < 4; ++i) {
        float qv = fminf(fmaxf(rintf(s4[i] * ss_inv), -32768.0f), 32767.0f) * scale_s;
        rq[i] = fminf(fmaxf(rintf((1.0f / qv) * sr_inv), -32768.0f), 32767.0f) * scale_r;
    }

    const size_t base = ((size_t)(b * Jdim + jc * JC)) * Cdim + c0;
    if (UC) {
        c4 qv[16];
#pragma unroll
        for (int j = 0; j < 16; ++j)                // all 16 rows in flight
            qv[j] = *reinterpret_cast<const c4*>(codes + base + (size_t)j * Cdim);
#pragma unroll
        for (int j = 0; j < 16; ++j) {
            const float e0 = eq_from((float)qv[j][0] * s, gm[0], ssub_inv, ssub) * rq[0];
            const float e1 = eq_from((float)qv[j][1] * s, gm[1], ssub_inv, ssub) * rq[1];
            const float e2 = eq_from((float)qv[j][2] * s, gm[2], ssub_inv, ssub) * rq[2];
            const float e3 = eq_from((float)qv[j][3] * s, gm[3], ssub_inv, ssub) * rq[3];
            f4 o;
            o[0] = fminf(fmaxf(rintf(e0 * so_inv), -128.0f), 127.0f) * scale_out;
            o[1] = fminf(fmaxf(rintf(e1 * so_inv), -128.0f), 127.0f) * scale_out;
            o[2] = fminf(fmaxf(rintf(e2 * so_inv), -128.0f), 127.0f) * scale_out;
            o[3] = fminf(fmaxf(rintf(e3 * so_inv), -128.0f), 127.0f) * scale_out;
            __builtin_nontemporal_store(o,
                reinterpret_cast<f4*>(out + base + (size_t)j * Cdim));
        }
    } else {
#pragma unroll
        for (int r0 = 0; r0 < JC; r0 += 8) {
            f4 xv[8];
#pragma unroll
            for (int j = 0; j < 8; ++j)
                xv[j] = *reinterpret_cast<const f4*>(x + base + (size_t)(r0 + j) * Cdim);
#pragma unroll
            for (int j = 0; j < 8; ++j) {
                const float e0 = eq_from(code8f(xv[j][0], sinv) * s, gm[0], ssub_inv, ssub) * rq[0];
                const float e1 = eq_from(code8f(xv[j][1], sinv) * s, gm[1], ssub_inv, ssub) * rq[1];
                const float e2 = eq_from(code8f(xv[j][2], sinv) * s, gm[2], ssub_inv, ssub) * rq[2];
                const float e3 = eq_from(code8f(xv[j][3], sinv) * s, gm[3], ssub_inv, ssub) * rq[3];
                f4 o;
                o[0] = fminf(fmaxf(rintf(e0 * so_inv), -128.0f), 127.0f) * scale_out;
                o[1] = fminf(fmaxf(rintf(e1 * so_inv), -128.0f), 127.0f) * scale_out;
                o[2] = fminf(fmaxf(rintf(e2 * so_inv), -128.0f), 127.0f) * scale_out;
                o[3] = fminf(fmaxf(rintf(e3 * so_inv), -128.0f), 127.0f) * scale_out;
                __builtin_nontemporal_store(o,
                    reinterpret_cast<f4*>(out + base + (size_t)(r0 + j) * Cdim));
            }
        }
    }
}

extern "C" void kernel_launch(void* const* d_in, const int* in_sizes, int n_in,
                              void* d_out, int out_size, void* d_ws, size_t ws_size,
                              hipStream_t stream) {
    const float* x     = (const float*)d_in[0];
    const float* scale = (const float*)d_in[1];
    float* out = (float*)d_out;
    char* ws   = (char*)d_ws;

    if (ws_size >= WS_NEED) {
        k_p1<true ><<<GRID1, 256, 0, stream>>>(x, scale, ws);
        k_r1<<<NG / 128, 256, 0, stream>>>(scale, ws);
        k_p2<true ><<<GRID2, 256, 0, stream>>>(x, scale, ws);
        k_r2<<<NG / 32, 256, 0, stream>>>(ws);
        k_p3<true ><<<GRID1, 256, 0, stream>>>(x, scale, ws, out);
    } else {
        // no-codes fallback: K3/K5 recompute xq from x (bit-identical)
        k_p1<false><<<GRID1, 256, 0, stream>>>(x, scale, ws);
        k_r1<<<NG / 128, 256, 0, stream>>>(scale, ws);
        k_p2<false><<<GRID2, 256, 0, stream>>>(x, scale, ws);
        k_r2<<<NG / 32, 256, 0, stream>>>(ws);
        k_p3<false><<<GRID1, 256, 0, stream>>>(x, scale, ws, out);
    }
}

// Round 14
// 95.026 us; speedup vs baseline: 1.0279x; 1.0279x over previous
//
#include <hip/hip_runtime.h>
#include <math.h>

// Quantized softmax over axis 1 of x(8, 4096, 1024) fp32.
// Groups: (b, c) column, 8192 groups of 4096 elements (stride 1024 floats).
//
// FINAL (= Round-12, 95.2us best). Round-13's micro-levers (P2 JC2=32,
// P3 16-deep) both regressed (-2.5us) -> reverted. Ceiling accounting:
// 268MB compulsory I/O (~42us) + ~100MB aux codes/partials (~16us) +
// 5 dependency-chained launches (~10us) + exp VALU (~10us) => ~85us floor;
// this config = 95us. Fusion alternatives tested to destruction:
// grid syncs ~50us each (R10), col-slab <2TB/s (R8/R9), LDS slab caps
// occupancy (R5), LUT gather conflicts (R6).
//   K1 p1: x (NT, 8-deep) -> codes(32MB) + [jc][g] max/min partials.
//   K2 r1: partials (c4-vectorized) -> gmv[g] + global amax_sub (atomicMax).
//   K3 p2: codes (8-deep, JC2=64) -> psum[64][8192].
//   K4 r2: psum -> sarr[g] + global max/min s (atomics).
//   K5 p3: codes (8-deep) + scalars -> out (NT stores).
// Atomics: uint max/min only (order-independent -> deterministic).

typedef float       f4 __attribute__((ext_vector_type(4)));
typedef signed char c4 __attribute__((ext_vector_type(4)));

static constexpr int Bdim = 8;
static constexpr int Jdim = 4096;
static constexpr int Cdim = 1024;
static constexpr int NG   = Bdim * Cdim;       // 8192 groups

static constexpr int JC    = 16;               // rows per P1/P3 chunk
static constexpr int NJC   = Jdim / JC;        // 256
static constexpr int GRID1 = Bdim * NJC;       // 2048
static constexpr int JC2   = 64;               // rows per P2 chunk
static constexpr int NJC2  = Jdim / JC2;       // 64
static constexpr int GRID2 = Bdim * NJC2;      // 512

// ---- ws byte offsets ----
static constexpr size_t SC_B    = 0;                               // f32[3]
static constexpr size_t GMV_B   = 4096;                            // f32[8192] gmax CODE
static constexpr size_t SARR_B  = GMV_B + (size_t)NG * 4;          // f32[8192]
static constexpr size_t PMAX_B  = 131072;                          // i8[256][8192]
static constexpr size_t PMIN_B  = PMAX_B + (size_t)NJC * NG;
static constexpr size_t PSUM_B  = PMIN_B + (size_t)NJC * NG;       // f32[64][8192] = 2MB
static constexpr size_t CODES_B = PSUM_B + (size_t)NJC * NG * 4;   // i8 32MB
static constexpr size_t WS_NEED = CODES_B + (size_t)Bdim * Jdim * Cdim;  // ~44MB

__device__ __forceinline__ float code8f(float x, float sinv) {
    // int8 code as float; rintf = round-half-even matches jnp.round
    return fminf(fmaxf(rintf(x * sinv), -128.0f), 127.0f);
}
// e_q = fq16(exp(fq16(clip(xq - gmax, -12, 0)))); scale_e = 1/32767 exactly
// (group-max element has sub==0 -> e==1 -> absmax(e)==1).
__device__ __forceinline__ float eq_from(float xq, float gmv, float ssub_inv, float ssub) {
    float sub = fminf(fmaxf(xq - gmv, -12.0f), 0.0f);
    float q   = rintf(sub * ssub_inv);
    float e   = __expf(q * ssub);
    return rintf(e * 32767.0f) * (1.0f / 32767.0f);
}
__device__ __forceinline__ f4 fmax4v(f4 a, f4 b) {
    f4 r; r[0]=fmaxf(a[0],b[0]); r[1]=fmaxf(a[1],b[1]);
    r[2]=fmaxf(a[2],b[2]); r[3]=fmaxf(a[3],b[3]); return r;
}
__device__ __forceinline__ f4 fmin4v(f4 a, f4 b) {
    f4 r; r[0]=fminf(a[0],b[0]); r[1]=fminf(a[1],b[1]);
    r[2]=fminf(a[2],b[2]); r[3]=fminf(a[3],b[3]); return r;
}

// ---------------- K1: quantize pass ----------------
template <bool WC>
__global__ __launch_bounds__(256) void k_p1(const float* __restrict__ x,
                                            const float* __restrict__ scale,
                                            char* __restrict__ ws) {
    float* sc = (float*)(ws + SC_B);
    if (blockIdx.x == 0 && threadIdx.x == 0) {
        sc[0] = 0.0f;                        // amax_sub (atomicMax, >=0)
        sc[1] = 0.0f;                        // max_s    (atomicMax, >0)
        sc[2] = __int_as_float(0x7f800000);  // min_s = +inf (atomicMin)
    }
    const int b  = blockIdx.x / NJC;
    const int jc = blockIdx.x % NJC;
    const int c0 = threadIdx.x * 4;
    const float sinv = 1.0f / scale[0];
    const size_t base = ((size_t)(b * Jdim + jc * JC)) * Cdim + c0;
    signed char* codes = (signed char*)(ws + CODES_B);

    f4 vmax = {-1e30f, -1e30f, -1e30f, -1e30f};
    f4 vmin = { 1e30f,  1e30f,  1e30f,  1e30f};
#pragma unroll
    for (int r0 = 0; r0 < JC; r0 += 8) {
        f4 v[8];
#pragma unroll
        for (int j = 0; j < 8; ++j)                 // 8 loads in flight
            v[j] = __builtin_nontemporal_load(
                reinterpret_cast<const f4*>(x + base + (size_t)(r0 + j) * Cdim));
#pragma unroll
        for (int j = 0; j < 8; ++j) {
            f4 q;
            q[0] = code8f(v[j][0], sinv); q[1] = code8f(v[j][1], sinv);
            q[2] = code8f(v[j][2], sinv); q[3] = code8f(v[j][3], sinv);
            vmax = fmax4v(vmax, q); vmin = fmin4v(vmin, q);
            if (WC)
                *reinterpret_cast<c4*>(codes + base + (size_t)(r0 + j) * Cdim) =
                    (c4){(signed char)(int)q[0], (signed char)(int)q[1],
                         (signed char)(int)q[2], (signed char)(int)q[3]};
        }
    }
    const size_t pidx = (size_t)jc * NG + b * Cdim + c0;   // [jc][g] coalesced
    *reinterpret_cast<c4*>(ws + PMAX_B + pidx) =
        (c4){(signed char)(int)vmax[0], (signed char)(int)vmax[1],
             (signed char)(int)vmax[2], (signed char)(int)vmax[3]};
    *reinterpret_cast<c4*>(ws + PMIN_B + pidx) =
        (c4){(signed char)(int)vmin[0], (signed char)(int)vmin[1],
             (signed char)(int)vmin[2], (signed char)(int)vmin[3]};
}

// ---------------- K2: group gmax + global amax_sub (vectorized c4) ----------------
__global__ __launch_bounds__(256) void k_r1(const float* __restrict__ scale,
                                            char* __restrict__ ws) {
    const signed char* pmax8 = (const signed char*)(ws + PMAX_B);
    const signed char* pmin8 = (const signed char*)(ws + PMIN_B);
    float* gmv = (float*)(ws + GMV_B);
    float* sc  = (float*)(ws + SC_B);

    const int qi  = threadIdx.x & 31;             // quad index
    const int sub = threadIdx.x >> 5;             // 0..7
    const size_t g4 = (size_t)blockIdx.x * 128 + qi * 4;

    int mx0 = -128, mx1 = -128, mx2 = -128, mx3 = -128;
    int mn0 =  127, mn1 =  127, mn2 =  127, mn3 =  127;
    for (int jc = sub; jc < NJC; jc += 8) {
        const c4 a = *reinterpret_cast<const c4*>(pmax8 + (size_t)jc * NG + g4);
        const c4 b = *reinterpret_cast<const c4*>(pmin8 + (size_t)jc * NG + g4);
        mx0 = max(mx0, (int)a[0]); mx1 = max(mx1, (int)a[1]);
        mx2 = max(mx2, (int)a[2]); mx3 = max(mx3, (int)a[3]);
        mn0 = min(mn0, (int)b[0]); mn1 = min(mn1, (int)b[1]);
        mn2 = min(mn2, (int)b[2]); mn3 = min(mn3, (int)b[3]);
    }
    __shared__ int smx[8][32][4], smn[8][32][4];
    smx[sub][qi][0] = mx0; smx[sub][qi][1] = mx1;
    smx[sub][qi][2] = mx2; smx[sub][qi][3] = mx3;
    smn[sub][qi][0] = mn0; smn[sub][qi][1] = mn1;
    smn[sub][qi][2] = mn2; smn[sub][qi][3] = mn3;
    __syncthreads();
    for (int off = 4; off; off >>= 1) {
        if (sub < off) {
#pragma unroll
            for (int i = 0; i < 4; ++i) {
                smx[sub][qi][i] = max(smx[sub][qi][i], smx[sub + off][qi][i]);
                smn[sub][qi][i] = min(smn[sub][qi][i], smn[sub + off][qi][i]);
            }
        }
        __syncthreads();
    }
    __shared__ float sd[32];
    if (sub == 0) {
        const float s = scale[0];
        f4 gq;
        float d = -1e30f;
#pragma unroll
        for (int i = 0; i < 4; ++i) {
            const float gx = (float)smx[0][qi][i];
            gq[i] = gx;
            d = fmaxf(d, fminf(12.0f, gx * s - (float)smn[0][qi][i] * s));
        }
        *reinterpret_cast<f4*>(gmv + g4) = gq;    // CODE values; consumers *s
        sd[qi] = d;
    }
    __syncthreads();
    if (threadIdx.x == 0) {
        float m = sd[0];
#pragma unroll
        for (int i = 1; i < 32; ++i) m = fmaxf(m, sd[i]);
        atomicMax(reinterpret_cast<unsigned int*>(sc + 0), __float_as_uint(m));
    }
}

// ---------------- K3: partial e_q sums, JC2=64 rows/block ----------------
template <bool UC>
__global__ __launch_bounds__(256) void k_p2(const float* __restrict__ x,
                                            const float* __restrict__ scale,
                                            char* __restrict__ ws) {
    const int b  = blockIdx.x / NJC2;
    const int jq = blockIdx.x % NJC2;
    const int c0 = threadIdx.x * 4;
    const float s = scale[0];
    const float sinv = 1.0f / s;
    const float* sc  = (const float*)(ws + SC_B);
    const float* gmv = (const float*)(ws + GMV_B);
    float* psum = (float*)(ws + PSUM_B);
    const signed char* codes = (const signed char*)(ws + CODES_B);

    const float amax = fmaxf(sc[0], 1e-9f);
    const float ssub = amax / 32767.0f;
    const float ssub_inv = 1.0f / ssub;
    const f4 gmc = *reinterpret_cast<const f4*>(gmv + b * Cdim + c0);
    const f4 gm  = {gmc[0] * s, gmc[1] * s, gmc[2] * s, gmc[3] * s};
    const size_t base = ((size_t)(b * Jdim + jq * JC2)) * Cdim + c0;

    f4 acc = {0.f, 0.f, 0.f, 0.f};
#pragma unroll
    for (int r0 = 0; r0 < JC2; r0 += 8) {
        c4 qv[8];
        f4 xv[8];
#pragma unroll
        for (int j = 0; j < 8; ++j) {               // 8 loads in flight
            if (UC)
                qv[j] = *reinterpret_cast<const c4*>(codes + base + (size_t)(r0 + j) * Cdim);
            else
                xv[j] = *reinterpret_cast<const f4*>(x + base + (size_t)(r0 + j) * Cdim);
        }
#pragma unroll
        for (int j = 0; j < 8; ++j) {
            float xq0, xq1, xq2, xq3;
            if (UC) {
                xq0 = (float)qv[j][0] * s; xq1 = (float)qv[j][1] * s;
                xq2 = (float)qv[j][2] * s; xq3 = (float)qv[j][3] * s;
            } else {
                xq0 = code8f(xv[j][0], sinv) * s; xq1 = code8f(xv[j][1], sinv) * s;
                xq2 = code8f(xv[j][2], sinv) * s; xq3 = code8f(xv[j][3], sinv) * s;
            }
            acc[0] += eq_from(xq0, gm[0], ssub_inv, ssub);
            acc[1] += eq_from(xq1, gm[1], ssub_inv, ssub);
            acc[2] += eq_from(xq2, gm[2], ssub_inv, ssub);
            acc[3] += eq_from(xq3, gm[3], ssub_inv, ssub);
        }
    }
    *reinterpret_cast<f4*>(psum + (size_t)jq * NG + b * Cdim + c0) = acc;  // [jq][g]
}

// ---------------- K4: group sums + global max/min s (64 chunks) ----------------
__global__ __launch_bounds__(256) void k_r2(char* __restrict__ ws) {
    const float* psum = (const float*)(ws + PSUM_B);
    float* sarr = (float*)(ws + SARR_B);
    float* sc   = (float*)(ws + SC_B);

    const int ci  = threadIdx.x & 31;
    const int sub = threadIdx.x >> 5;
    const int g   = blockIdx.x * 32 + ci;

    float p = 0.0f;
    for (int ch = sub; ch < NJC2; ch += 8)         // ascending, step 8
        p += psum[(size_t)ch * NG + g];
    __shared__ float sp[8][32];
    sp[sub][ci] = p;
    __syncthreads();
    for (int off = 4; off; off >>= 1) {
        if (sub < off) sp[sub][ci] += sp[sub + off][ci];
        __syncthreads();
    }
    __shared__ float smx[32], smn[32];
    if (sub == 0) {
        const float tv = sp[0][ci];
        sarr[g] = tv;
        smx[ci] = tv; smn[ci] = tv;
    }
    __syncthreads();
    if (threadIdx.x == 0) {
        float mx = smx[0], mn = smn[0];
#pragma unroll
        for (int i = 1; i < 32; ++i) { mx = fmaxf(mx, smx[i]); mn = fminf(mn, smn[i]); }
        atomicMax(reinterpret_cast<unsigned int*>(sc + 1), __float_as_uint(mx));
        atomicMin(reinterpret_cast<unsigned int*>(sc + 2), __float_as_uint(mn));
    }
}

// ---------------- K5: output pass ----------------
template <bool UC>
__global__ __launch_bounds__(256) void k_p3(const float* __restrict__ x,
                                            const float* __restrict__ scale,
                                            const char* __restrict__ ws,
                                            float* __restrict__ out) {
    const int b  = blockIdx.x / NJC;
    const int jc = blockIdx.x % NJC;
    const int c0 = threadIdx.x * 4;
    const float s = scale[0];
    const float sinv = 1.0f / s;
    const float* sc   = (const float*)(ws + SC_B);
    const float* gmv  = (const float*)(ws + GMV_B);
    const float* sarr = (const float*)(ws + SARR_B);
    const signed char* codes = (const signed char*)(ws + CODES_B);

    const float amax = fmaxf(sc[0], 1e-9f);
    const float ssub = amax / 32767.0f;
    const float ssub_inv = 1.0f / ssub;

    const float max_s = sc[1];
    const float min_s = sc[2];
    // fq monotone: min s_q = fq(min s); max r = 1/min s_q; max r_q = fq(max r)
    const float scale_s = fmaxf(max_s, 1e-9f) / 32767.0f;
    const float ss_inv  = 1.0f / scale_s;
    const float minsq   = fminf(fmaxf(rintf(min_s * ss_inv), -32768.0f), 32767.0f) * scale_s;
    const float maxr    = 1.0f / minsq;
    const float scale_r = fmaxf(maxr, 1e-9f) / 32767.0f;
    const float sr_inv  = 1.0f / scale_r;
    const float maxrq   = fminf(fmaxf(rintf(maxr * sr_inv), -32768.0f), 32767.0f) * scale_r;
    const float scale_out = fmaxf(maxrq, 1e-9f) / 127.0f;
    const float so_inv  = 1.0f / scale_out;

    const f4 gmc = *reinterpret_cast<const f4*>(gmv + b * Cdim + c0);
    const f4 gm  = {gmc[0] * s, gmc[1] * s, gmc[2] * s, gmc[3] * s};
    const f4 s4  = *reinterpret_cast<const f4*>(sarr + b * Cdim + c0);

    f4 rq;
#pragma unroll
    for (int i = 0; i < 4; ++i) {
        float qv = fminf(fmaxf(rintf(s4[i] * ss_inv), -32768.0f), 32767.0f) * scale_s;
        rq[i] = fminf(fmaxf(rintf((1.0f / qv) * sr_inv), -32768.0f), 32767.0f) * scale_r;
    }

    const size_t base = ((size_t)(b * Jdim + jc * JC)) * Cdim + c0;
#pragma unroll
    for (int r0 = 0; r0 < JC; r0 += 8) {
        c4 qv[8];
        f4 xv[8];
#pragma unroll
        for (int j = 0; j < 8; ++j) {               // 8 loads in flight
            if (UC)
                qv[j] = *reinterpret_cast<const c4*>(codes + base + (size_t)(r0 + j) * Cdim);
            else
                xv[j] = *reinterpret_cast<const f4*>(x + base + (size_t)(r0 + j) * Cdim);
        }
#pragma unroll
        for (int j = 0; j < 8; ++j) {
            float xq0, xq1, xq2, xq3;
            if (UC) {
                xq0 = (float)qv[j][0] * s; xq1 = (float)qv[j][1] * s;
                xq2 = (float)qv[j][2] * s; xq3 = (float)qv[j][3] * s;
            } else {
                xq0 = code8f(xv[j][0], sinv) * s; xq1 = code8f(xv[j][1], sinv) * s;
                xq2 = code8f(xv[j][2], sinv) * s; xq3 = code8f(xv[j][3], sinv) * s;
            }
            const float e0 = eq_from(xq0, gm[0], ssub_inv, ssub) * rq[0];
            const float e1 = eq_from(xq1, gm[1], ssub_inv, ssub) * rq[1];
            const float e2 = eq_from(xq2, gm[2], ssub_inv, ssub) * rq[2];
            const float e3 = eq_from(xq3, gm[3], ssub_inv, ssub) * rq[3];
            f4 o;
            o[0] = fminf(fmaxf(rintf(e0 * so_inv), -128.0f), 127.0f) * scale_out;
            o[1] = fminf(fmaxf(rintf(e1 * so_inv), -128.0f), 127.0f) * scale_out;
            o[2] = fminf(fmaxf(rintf(e2 * so_inv), -128.0f), 127.0f) * scale_out;
            o[3] = fminf(fmaxf(rintf(e3 * so_inv), -128.0f), 127.0f) * scale_out;
            __builtin_nontemporal_store(o,
                reinterpret_cast<f4*>(out + base + (size_t)(r0 + j) * Cdim));
        }
    }
}

extern "C" void kernel_launch(void* const* d_in, const int* in_sizes, int n_in,
                              void* d_out, int out_size, void* d_ws, size_t ws_size,
                              hipStream_t stream) {
    const float* x     = (const float*)d_in[0];
    const float* scale = (const float*)d_in[1];
    float* out = (float*)d_out;
    char* ws   = (char*)d_ws;

    if (ws_size >= WS_NEED) {
        k_p1<true ><<<GRID1, 256, 0, stream>>>(x, scale, ws);
        k_r1<<<NG / 128, 256, 0, stream>>>(scale, ws);
        k_p2<true ><<<GRID2, 256, 0, stream>>>(x, scale, ws);
        k_r2<<<NG / 32, 256, 0, stream>>>(ws);
        k_p3<true ><<<GRID1, 256, 0, stream>>>(x, scale, ws, out);
    } else {
        // no-codes fallback: K3/K5 recompute xq from x (bit-identical)
        k_p1<false><<<GRID1, 256, 0, stream>>>(x, scale, ws);
        k_r1<<<NG / 128, 256, 0, stream>>>(scale, ws);
        k_p2<false><<<GRID2, 256, 0, stream>>>(x, scale, ws);
        k_r2<<<NG / 32, 256, 0, stream>>>(ws);
        k_p3<false><<<GRID1, 256, 0, stream>>>(x, scale, ws, out);
    }
}